// Round 3
// baseline (806.833 us; speedup 1.0000x reference)
//
#include <hip/hip_runtime.h>

typedef unsigned int u32;
typedef unsigned short u16;
typedef __bf16 bf16x8 __attribute__((ext_vector_type(8)));
typedef float floatx4 __attribute__((ext_vector_type(4)));

__device__ __forceinline__ u16 f2bf(float f) {
  u32 u = __float_as_uint(f);
  u += 0x7fffu + ((u >> 16) & 1u);
  return (u16)(u >> 16);
}
__device__ __forceinline__ float bf2f(u16 h) { return __uint_as_float(((u32)h) << 16); }

// ---------------- runtime dtype probe ----------------
// flags[0] = 1 if x/W/b are fp32 (else bf16);  flags[1] = 1 if edge_index is int64 (else int32)
__global__ void probe_dtypes(const u16* __restrict__ xs, const u32* __restrict__ eis,
                             int* __restrict__ flags) {
  if (threadIdx.x == 0 && blockIdx.x == 0) {
    int big = 0;
    for (int i = 0; i < 4096; i++) {
      u32 e = (xs[i] >> 7) & 0xffu;           // bf16 exponent field
      if (e >= 0xC0u) big++;                  // |v| >= 2^65: impossible for N(0,1) bf16
    }
    flags[0] = (big > 16) ? 1 : 0;
    int odd_nz = 0;
    for (int i = 0; i < 256; i++)
      if (eis[2 * i + 1] != 0u) odd_nz++;     // int64 hi-words of values < 2^31 are all 0
    flags[1] = (odd_nz == 0) ? 1 : 0;
  }
}

// ---------------- CSR construction ----------------

__global__ void count_deg(const int* __restrict__ ei, const int* __restrict__ flags,
                          int* __restrict__ deg, int e) {
  int i = blockIdx.x * 256 + threadIdx.x;
  if (i < e) {
    int d = flags[1] ? ei[2 * (e + i)] : ei[e + i];
    atomicAdd(&deg[d], 1);
  }
}

__global__ void compute_dinv(const int* __restrict__ deg, float* __restrict__ dinv, int n) {
  int i = blockIdx.x * 256 + threadIdx.x;
  if (i < n) dinv[i] = rsqrtf((float)(deg[i] + 1));  // +1 self-loop, always > 0
}

__global__ __launch_bounds__(1024) void scan_block(const int* __restrict__ deg,
                                                   int* __restrict__ rp,
                                                   int* __restrict__ bsum, int n) {
  __shared__ int sm[1024];
  int gid = blockIdx.x * 1024 + threadIdx.x;
  int x = (gid < n) ? deg[gid] : 0;
  sm[threadIdx.x] = x;
  __syncthreads();
  for (int off = 1; off < 1024; off <<= 1) {
    int t = (threadIdx.x >= off) ? sm[threadIdx.x - off] : 0;
    __syncthreads();
    sm[threadIdx.x] += t;
    __syncthreads();
  }
  if (gid < n) rp[gid + 1] = sm[threadIdx.x];  // inclusive within block
  if (threadIdx.x == 1023) bsum[blockIdx.x] = sm[1023];
}

__global__ void scan_tops(int* __restrict__ bsum, int nb) {
  if (blockIdx.x == 0 && threadIdx.x == 0) {
    int run = 0;
    for (int b = 0; b < nb; b++) { int t = bsum[b]; bsum[b] = run; run += t; }
  }
}

__global__ void scan_add(int* __restrict__ rp, const int* __restrict__ bsum, int n) {
  int i = blockIdx.x * 256 + threadIdx.x;
  if (i == 0) rp[0] = 0;
  if (i < n) rp[i + 1] += bsum[i >> 10];
}

__global__ void fill_csr(const int* __restrict__ ei, const int* __restrict__ flags,
                         const int* __restrict__ rp, int* __restrict__ cnt,
                         int* __restrict__ csr, int e) {
  int i = blockIdx.x * 256 + threadIdx.x;
  if (i < e) {
    int s, d;
    if (flags[1]) { s = ei[2 * i]; d = ei[2 * (e + i)]; }
    else          { s = ei[i];     d = ei[e + i]; }
    int pos = rp[d] + atomicAdd(&cnt[d], 1);
    csr[pos] = s;
  }
}

// ---------------- bf16 MFMA GEMM: Y[nrows,OUT] = X[nrows,128] @ W[128,OUT] ----------------
// A-frag: A[m=lane&15][k=(lane>>4)*8+j]; B-frag: B[k=(lane>>4)*8+j][n=lane&15]
// C/D: col=lane&15, row=(lane>>4)*4+reg  (m89/m91-verified mapping)
// XPROBED: X is a harness input, dtype per flags[0]. Otherwise X is internal bf16 ALWAYS.

template <int OUT, bool XPROBED>
__global__ __launch_bounds__(256) void gemm_x_w(const void* __restrict__ Xv,
                                                const void* __restrict__ Wv,
                                                const int* __restrict__ flags,
                                                u16* __restrict__ Y, int nrows) {
  constexpr int K = 128;
  constexpr int NT = OUT / 16;
  constexpr int LDW = K + 8;
  __shared__ u16 Wt[OUT * LDW];
  const int wf32 = flags[0];
  const int xf32 = XPROBED ? wf32 : 0;
  int tid = threadIdx.x;
  if (wf32) {
    const float* Wf = (const float*)Wv;
    for (int idx = tid; idx < K * OUT; idx += 256) {
      int k = idx / OUT, n = idx % OUT;
      Wt[n * LDW + k] = f2bf(Wf[idx]);
    }
  } else {
    const u16* Wu = (const u16*)Wv;
    for (int idx = tid; idx < K * OUT; idx += 256) {
      int k = idx / OUT, n = idx % OUT;
      Wt[n * LDW + k] = Wu[idx];
    }
  }
  __syncthreads();
  int lane = tid & 63, wave = tid >> 6;
  int quad = lane >> 4, low = lane & 15;
  int mBase = blockIdx.x * 64 + wave * 16;
  int m = mBase + low;
  int ml = (m < nrows) ? m : (nrows - 1);  // clamp: rows independent, stores guarded
  floatx4 acc[NT];
#pragma unroll
  for (int i = 0; i < NT; i++) acc[i] = (floatx4)0.0f;
#pragma unroll
  for (int kb = 0; kb < 4; kb++) {
    int k0 = kb * 32 + quad * 8;
    bf16x8 a;
    if (xf32) {
      const float* Xf = (const float*)Xv;
      floatx4 p0 = *(const floatx4*)(Xf + (size_t)ml * K + k0);
      floatx4 p1 = *(const floatx4*)(Xf + (size_t)ml * K + k0 + 4);
      union { bf16x8 v; u16 s[8]; } au;
#pragma unroll
      for (int j = 0; j < 4; j++) { au.s[j] = f2bf(p0[j]); au.s[4 + j] = f2bf(p1[j]); }
      a = au.v;
    } else {
      a = *(const bf16x8*)((const u16*)Xv + (size_t)ml * K + k0);
    }
#pragma unroll
    for (int nt = 0; nt < NT; nt++) {
      bf16x8 b = *(const bf16x8*)(&Wt[(nt * 16 + low) * LDW + k0]);
      acc[nt] = __builtin_amdgcn_mfma_f32_16x16x32_bf16(a, b, acc[nt], 0, 0, 0);
    }
  }
#pragma unroll
  for (int nt = 0; nt < NT; nt++) {
    int col = nt * 16 + low;
#pragma unroll
    for (int r = 0; r < 4; r++) {
      int row = mBase + quad * 4 + r;
      if (row < nrows) Y[(size_t)row * OUT + col] = f2bf(acc[nt][r]);
    }
  }
}

// ---------------- aggregation: out[d] = act( dinv[d]*(sum_e dinv[s]*h[s] + dinv[d]*h[d]) + b ) ----

// 128 channels: 1 wave/node, 2 bf16 ch per lane; H internal bf16 always
__global__ __launch_bounds__(256) void agg_128(const u32* __restrict__ H,
                                               const int* __restrict__ rp,
                                               const int* __restrict__ cs,
                                               const float* __restrict__ dinv,
                                               const void* __restrict__ biasv,
                                               const int* __restrict__ flags,
                                               u32* __restrict__ out, int n) {
  int node = blockIdx.x * 4 + (threadIdx.x >> 6);
  if (node >= n) return;
  int lane = threadIdx.x & 63;
  int s0 = rp[node], s1 = rp[node + 1];
  float ax = 0.f, ay = 0.f;
  for (int base = s0; base < s1; base += 64) {
    int nb = s1 - base; if (nb > 64) nb = 64;
    int src = 0; float dv = 0.f;
    if (lane < nb) { src = cs[base + lane]; dv = dinv[src]; }
    int j = 0;
    for (; j + 4 <= nb; j += 4) {
      int s_0 = __shfl(src, j), s_1 = __shfl(src, j + 1);
      int s_2 = __shfl(src, j + 2), s_3 = __shfl(src, j + 3);
      float w_0 = __shfl(dv, j), w_1 = __shfl(dv, j + 1);
      float w_2 = __shfl(dv, j + 2), w_3 = __shfl(dv, j + 3);
      u32 v0 = H[(size_t)s_0 * 64 + lane];
      u32 v1 = H[(size_t)s_1 * 64 + lane];
      u32 v2 = H[(size_t)s_2 * 64 + lane];
      u32 v3 = H[(size_t)s_3 * 64 + lane];
      ax += w_0 * __uint_as_float(v0 << 16); ay += w_0 * __uint_as_float(v0 & 0xffff0000u);
      ax += w_1 * __uint_as_float(v1 << 16); ay += w_1 * __uint_as_float(v1 & 0xffff0000u);
      ax += w_2 * __uint_as_float(v2 << 16); ay += w_2 * __uint_as_float(v2 & 0xffff0000u);
      ax += w_3 * __uint_as_float(v3 << 16); ay += w_3 * __uint_as_float(v3 & 0xffff0000u);
    }
    for (; j < nb; j++) {
      int sj = __shfl(src, j);
      float wj = __shfl(dv, j);
      u32 v = H[(size_t)sj * 64 + lane];
      ax += wj * __uint_as_float(v << 16); ay += wj * __uint_as_float(v & 0xffff0000u);
    }
  }
  float ds = dinv[node];
  u32 vs = H[(size_t)node * 64 + lane];
  float r0 = ds * (ax + ds * __uint_as_float(vs << 16));
  float r1 = ds * (ay + ds * __uint_as_float(vs & 0xffff0000u));
  float bx, by;
  if (flags[0]) {
    const float* bf = (const float*)biasv;
    bx = bf[2 * lane]; by = bf[2 * lane + 1];
  } else {
    u32 bb = ((const u32*)biasv)[lane];
    bx = __uint_as_float(bb << 16); by = __uint_as_float(bb & 0xffff0000u);
  }
  r0 = fmaxf(r0 + bx, 0.f); r1 = fmaxf(r1 + by, 0.f);  // layer-1 ReLU
  out[(size_t)node * 64 + lane] = (u32)f2bf(r0) | ((u32)f2bf(r1) << 16);
}

// 64 channels: 1 wave/node, 1 ch per lane; no ReLU; output dtype per flags[0]
__global__ __launch_bounds__(256) void agg_64(const u16* __restrict__ H,
                                              const int* __restrict__ rp,
                                              const int* __restrict__ cs,
                                              const float* __restrict__ dinv,
                                              const void* __restrict__ biasv,
                                              const int* __restrict__ flags,
                                              void* __restrict__ outv, int n) {
  int node = blockIdx.x * 4 + (threadIdx.x >> 6);
  if (node >= n) return;
  int lane = threadIdx.x & 63;
  int s0 = rp[node], s1 = rp[node + 1];
  float a = 0.f;
  for (int base = s0; base < s1; base += 64) {
    int nb = s1 - base; if (nb > 64) nb = 64;
    int src = 0; float dv = 0.f;
    if (lane < nb) { src = cs[base + lane]; dv = dinv[src]; }
    int j = 0;
    for (; j + 4 <= nb; j += 4) {
      int s_0 = __shfl(src, j), s_1 = __shfl(src, j + 1);
      int s_2 = __shfl(src, j + 2), s_3 = __shfl(src, j + 3);
      float w_0 = __shfl(dv, j), w_1 = __shfl(dv, j + 1);
      float w_2 = __shfl(dv, j + 2), w_3 = __shfl(dv, j + 3);
      float f0 = bf2f(H[(size_t)s_0 * 64 + lane]);
      float f1 = bf2f(H[(size_t)s_1 * 64 + lane]);
      float f2 = bf2f(H[(size_t)s_2 * 64 + lane]);
      float f3 = bf2f(H[(size_t)s_3 * 64 + lane]);
      a += w_0 * f0; a += w_1 * f1; a += w_2 * f2; a += w_3 * f3;
    }
    for (; j < nb; j++) {
      int sj = __shfl(src, j);
      float wj = __shfl(dv, j);
      a += wj * bf2f(H[(size_t)sj * 64 + lane]);
    }
  }
  float ds = dinv[node];
  float fs = bf2f(H[(size_t)node * 64 + lane]);
  float bz = flags[0] ? ((const float*)biasv)[lane] : bf2f(((const u16*)biasv)[lane]);
  float r = ds * (a + ds * fs) + bz;
  if (flags[0]) ((float*)outv)[(size_t)node * 64 + lane] = r;
  else          ((u16*)outv)[(size_t)node * 64 + lane] = f2bf(r);
}

// ---------------- launch ----------------

extern "C" void kernel_launch(void* const* d_in, const int* in_sizes, int n_in,
                              void* d_out, int out_size, void* d_ws, size_t ws_size,
                              hipStream_t stream) {
  const void* x  = d_in[0];
  const int*  ei = (const int*)d_in[1];
  const void* W1 = d_in[2];
  const void* b1 = d_in[3];
  const void* W2 = d_in[4];
  const void* b2 = d_in[5];
  const int N = in_sizes[0] / 128;
  const int E = in_sizes[1] / 2;

  auto al = [](size_t v) { return (v + 15) & ~(size_t)15; };
  char* ws = (char*)d_ws;
  size_t o = 0;
  int*   flags = (int*)(ws + o); o += 256;
  int*   deg  = (int*)(ws + o);   o += al((size_t)N * 4);        // reused as cnt for fill
  int*   rp   = (int*)(ws + o);   o += al((size_t)(N + 1) * 4);
  float* dinv = (float*)(ws + o); o += al((size_t)N * 4);
  int*   csr  = (int*)(ws + o);   o += al((size_t)E * 4);
  u16*   h    = (u16*)(ws + o);   o += al((size_t)N * 128 * 2);  // layer1 pre-agg; reused as h2
  u16*   h1   = (u16*)(ws + o);   o += al((size_t)N * 128 * 2);  // layer1 post-agg (ReLU)
  int*   bsum = (int*)(ws + o);   o += 4096;
  u16*   h2   = h;  // gemm2 reads h1, writes here; h dead by then

  const int gE = (E + 255) / 256;
  const int gN = (N + 255) / 256;
  const int nb = (N + 1023) / 1024;

  probe_dtypes<<<1, 64, 0, stream>>>((const u16*)x, (const u32*)ei, flags);
  hipMemsetAsync(deg, 0, (size_t)N * 4, stream);
  count_deg<<<gE, 256, 0, stream>>>(ei, flags, deg, E);
  compute_dinv<<<gN, 256, 0, stream>>>(deg, dinv, N);
  scan_block<<<nb, 1024, 0, stream>>>(deg, rp, bsum, N);
  scan_tops<<<1, 64, 0, stream>>>(bsum, nb);
  scan_add<<<gN, 256, 0, stream>>>(rp, bsum, N);
  hipMemsetAsync(deg, 0, (size_t)N * 4, stream);  // now the fill counters
  fill_csr<<<gE, 256, 0, stream>>>(ei, flags, rp, deg, csr, E);

  // gemm1: X = harness input (dtype per probe). gemm2: X = internal bf16 h1 (ALWAYS bf16).
  gemm_x_w<128, true><<<(N + 63) / 64, 256, 0, stream>>>(x, W1, flags, h, N);
  agg_128<<<(N + 3) / 4, 256, 0, stream>>>((const u32*)h, rp, csr, dinv, b1, flags, (u32*)h1, N);
  gemm_x_w<64, false><<<(N + 63) / 64, 256, 0, stream>>>(h1, W2, flags, h2, N);
  agg_64<<<(N + 3) / 4, 256, 0, stream>>>(h2, rp, csr, dinv, b2, flags, d_out, N);
}

// Round 4
// 687.513 us; speedup vs baseline: 1.1736x; 1.1736x over previous
//
#include <hip/hip_runtime.h>

typedef unsigned int u32;
typedef unsigned short u16;
typedef __bf16 bf16x8 __attribute__((ext_vector_type(8)));
typedef float floatx4 __attribute__((ext_vector_type(4)));

__device__ __forceinline__ u16 f2bf(float f) {
  u32 u = __float_as_uint(f);
  u += 0x7fffu + ((u >> 16) & 1u);
  return (u16)(u >> 16);
}
__device__ __forceinline__ float bf2f(u16 h) { return __uint_as_float(((u32)h) << 16); }

// ---------------- runtime dtype probe ----------------
// flags[0] = 1 if x/W/b are fp32 (else bf16);  flags[1] = 1 if edge_index is int64 (else int32)
__global__ void probe_dtypes(const u16* __restrict__ xs, const u32* __restrict__ eis,
                             int* __restrict__ flags) {
  int lane = threadIdx.x;  // 64 threads
  int big = 0;
  for (int i = lane; i < 4096; i += 64) {
    u32 e = (xs[i] >> 7) & 0xffu;           // bf16 exponent field
    big += (e >= 0xC0u) ? 1 : 0;            // |v| >= 2^65: impossible for N(0,1) bf16
  }
  int odd = 0;
  for (int i = lane; i < 256; i += 64)
    odd += (eis[2 * i + 1] != 0u) ? 1 : 0;  // int64 hi-words of values < 2^31 are all 0
#pragma unroll
  for (int off = 32; off; off >>= 1) {
    big += __shfl_down(big, off);
    odd += __shfl_down(odd, off);
  }
  if (lane == 0 && blockIdx.x == 0) {
    flags[0] = (big > 16) ? 1 : 0;
    flags[1] = (odd == 0) ? 1 : 0;
  }
}

// ---------------- CSR construction ----------------

__global__ void count_deg(const int* __restrict__ ei, const int* __restrict__ flags,
                          int* __restrict__ deg, int e) {
  int i = blockIdx.x * 256 + threadIdx.x;
  if (i < e) {
    int d = flags[1] ? ei[2 * (e + i)] : ei[e + i];
    atomicAdd(&deg[d], 1);
  }
}

__global__ void compute_dinv(const int* __restrict__ deg, float* __restrict__ dinv, int n) {
  int i = blockIdx.x * 256 + threadIdx.x;
  if (i < n) dinv[i] = rsqrtf((float)(deg[i] + 1));  // +1 self-loop, always > 0
}

__global__ __launch_bounds__(1024) void scan_block(const int* __restrict__ deg,
                                                   int* __restrict__ rp,
                                                   int* __restrict__ bsum, int n) {
  __shared__ int sm[1024];
  int gid = blockIdx.x * 1024 + threadIdx.x;
  int x = (gid < n) ? deg[gid] : 0;
  sm[threadIdx.x] = x;
  __syncthreads();
  for (int off = 1; off < 1024; off <<= 1) {
    int t = (threadIdx.x >= off) ? sm[threadIdx.x - off] : 0;
    __syncthreads();
    sm[threadIdx.x] += t;
    __syncthreads();
  }
  if (gid < n) rp[gid + 1] = sm[threadIdx.x];  // inclusive within block
  if (threadIdx.x == 1023) bsum[blockIdx.x] = sm[1023];
}

__global__ void scan_tops(int* __restrict__ bsum, int nb) {
  if (blockIdx.x == 0 && threadIdx.x == 0) {
    int run = 0;
    for (int b = 0; b < nb; b++) { int t = bsum[b]; bsum[b] = run; run += t; }
  }
}

__global__ void scan_add(int* __restrict__ rp, const int* __restrict__ bsum, int n) {
  int i = blockIdx.x * 256 + threadIdx.x;
  if (i == 0) rp[0] = 0;
  if (i < n) rp[i + 1] += bsum[i >> 10];
}

// Partitioned fill: blocks with (blockIdx&7)==p only write csr slots for dst in slice p.
// Round-robin blockIdx->XCD means slice writes stay in ONE XCD's L2 -> full-line writebacks
// (fixes the 197 MB WRITE_SIZE / 15x amplification seen in round 3). Heuristic affects speed
// only: atomics are device-scope, stores flushed at dispatch end, any mapping is correct.
__global__ __launch_bounds__(256) void fill_csr_part(const int* __restrict__ ei,
                                                     const int* __restrict__ flags,
                                                     const int* __restrict__ rp,
                                                     int* __restrict__ cnt,
                                                     int* __restrict__ csr, int e, int n) {
  const int part = blockIdx.x & 7;
  const int bid = blockIdx.x >> 3;
  const int nblk = gridDim.x >> 3;
  const int slice = (n + 7) >> 3;
  const int lo = part * slice;
  const int hi = (lo + slice < n) ? lo + slice : n;
  const int i64 = flags[1];
  for (int i = bid * 256 + threadIdx.x; i < e; i += nblk * 256) {
    int d = i64 ? ei[2 * (e + i)] : ei[e + i];
    if (d >= lo && d < hi) {
      int s = i64 ? ei[2 * i] : ei[i];
      int pos = rp[d] + atomicAdd(&cnt[d], 1);
      csr[pos] = s;
    }
  }
}

// ---------------- bf16 MFMA GEMM: Y[nrows,OUT] = X[nrows,128] @ W[128,OUT] ----------------
// A-frag: A[m=lane&15][k=(lane>>4)*8+j]; B-frag: B[k=(lane>>4)*8+j][n=lane&15]
// C/D: col=lane&15, row=(lane>>4)*4+reg  (m89/m91-verified mapping)
// XPROBED: X is a harness input, dtype per flags[0]. Otherwise X is internal bf16 ALWAYS.

template <int OUT, bool XPROBED>
__global__ __launch_bounds__(256) void gemm_x_w(const void* __restrict__ Xv,
                                                const void* __restrict__ Wv,
                                                const int* __restrict__ flags,
                                                u16* __restrict__ Y, int nrows) {
  constexpr int K = 128;
  constexpr int NT = OUT / 16;
  constexpr int LDW = K + 8;
  __shared__ u16 Wt[OUT * LDW];
  const int wf32 = flags[0];
  const int xf32 = XPROBED ? wf32 : 0;
  int tid = threadIdx.x;
  if (wf32) {
    const float* Wf = (const float*)Wv;
    for (int idx = tid; idx < K * OUT; idx += 256) {
      int k = idx / OUT, n = idx % OUT;
      Wt[n * LDW + k] = f2bf(Wf[idx]);
    }
  } else {
    const u16* Wu = (const u16*)Wv;
    for (int idx = tid; idx < K * OUT; idx += 256) {
      int k = idx / OUT, n = idx % OUT;
      Wt[n * LDW + k] = Wu[idx];
    }
  }
  __syncthreads();
  int lane = tid & 63, wave = tid >> 6;
  int quad = lane >> 4, low = lane & 15;
  int mBase = blockIdx.x * 64 + wave * 16;
  int m = mBase + low;
  int ml = (m < nrows) ? m : (nrows - 1);  // clamp: rows independent, stores guarded
  floatx4 acc[NT];
#pragma unroll
  for (int i = 0; i < NT; i++) acc[i] = (floatx4)0.0f;
#pragma unroll
  for (int kb = 0; kb < 4; kb++) {
    int k0 = kb * 32 + quad * 8;
    bf16x8 a;
    if (xf32) {
      const float* Xf = (const float*)Xv;
      floatx4 p0 = *(const floatx4*)(Xf + (size_t)ml * K + k0);
      floatx4 p1 = *(const floatx4*)(Xf + (size_t)ml * K + k0 + 4);
      union { bf16x8 v; u16 s[8]; } au;
#pragma unroll
      for (int j = 0; j < 4; j++) { au.s[j] = f2bf(p0[j]); au.s[4 + j] = f2bf(p1[j]); }
      a = au.v;
    } else {
      a = *(const bf16x8*)((const u16*)Xv + (size_t)ml * K + k0);
    }
#pragma unroll
    for (int nt = 0; nt < NT; nt++) {
      bf16x8 b = *(const bf16x8*)(&Wt[(nt * 16 + low) * LDW + k0]);
      acc[nt] = __builtin_amdgcn_mfma_f32_16x16x32_bf16(a, b, acc[nt], 0, 0, 0);
    }
  }
#pragma unroll
  for (int nt = 0; nt < NT; nt++) {
    int col = nt * 16 + low;
#pragma unroll
    for (int r = 0; r < 4; r++) {
      int row = mBase + quad * 4 + r;
      if (row < nrows) Y[(size_t)row * OUT + col] = f2bf(acc[nt][r]);
    }
  }
}

// ---------------- aggregation: out[d] = act( dinv[d]*(sum_e dinv[s]*h[s] + dinv[d]*h[d]) + b ) ----

// 128 channels: 1 wave/node, 2 bf16 ch per lane; H internal bf16 always
__global__ __launch_bounds__(256) void agg_128(const u32* __restrict__ H,
                                               const int* __restrict__ rp,
                                               const int* __restrict__ cs,
                                               const float* __restrict__ dinv,
                                               const void* __restrict__ biasv,
                                               const int* __restrict__ flags,
                                               u32* __restrict__ out, int n) {
  int node = blockIdx.x * 4 + (threadIdx.x >> 6);
  if (node >= n) return;
  int lane = threadIdx.x & 63;
  int s0 = rp[node], s1 = rp[node + 1];
  float ax = 0.f, ay = 0.f;
  for (int base = s0; base < s1; base += 64) {
    int nb = s1 - base; if (nb > 64) nb = 64;
    int src = 0; float dv = 0.f;
    if (lane < nb) { src = cs[base + lane]; dv = dinv[src]; }
    int j = 0;
    for (; j + 4 <= nb; j += 4) {
      int s_0 = __shfl(src, j), s_1 = __shfl(src, j + 1);
      int s_2 = __shfl(src, j + 2), s_3 = __shfl(src, j + 3);
      float w_0 = __shfl(dv, j), w_1 = __shfl(dv, j + 1);
      float w_2 = __shfl(dv, j + 2), w_3 = __shfl(dv, j + 3);
      u32 v0 = H[(size_t)s_0 * 64 + lane];
      u32 v1 = H[(size_t)s_1 * 64 + lane];
      u32 v2 = H[(size_t)s_2 * 64 + lane];
      u32 v3 = H[(size_t)s_3 * 64 + lane];
      ax += w_0 * __uint_as_float(v0 << 16); ay += w_0 * __uint_as_float(v0 & 0xffff0000u);
      ax += w_1 * __uint_as_float(v1 << 16); ay += w_1 * __uint_as_float(v1 & 0xffff0000u);
      ax += w_2 * __uint_as_float(v2 << 16); ay += w_2 * __uint_as_float(v2 & 0xffff0000u);
      ax += w_3 * __uint_as_float(v3 << 16); ay += w_3 * __uint_as_float(v3 & 0xffff0000u);
    }
    for (; j < nb; j++) {
      int sj = __shfl(src, j);
      float wj = __shfl(dv, j);
      u32 v = H[(size_t)sj * 64 + lane];
      ax += wj * __uint_as_float(v << 16); ay += wj * __uint_as_float(v & 0xffff0000u);
    }
  }
  float ds = dinv[node];
  u32 vs = H[(size_t)node * 64 + lane];
  float r0 = ds * (ax + ds * __uint_as_float(vs << 16));
  float r1 = ds * (ay + ds * __uint_as_float(vs & 0xffff0000u));
  float bx, by;
  if (flags[0]) {
    const float* bf = (const float*)biasv;
    bx = bf[2 * lane]; by = bf[2 * lane + 1];
  } else {
    u32 bb = ((const u32*)biasv)[lane];
    bx = __uint_as_float(bb << 16); by = __uint_as_float(bb & 0xffff0000u);
  }
  r0 = fmaxf(r0 + bx, 0.f); r1 = fmaxf(r1 + by, 0.f);  // layer-1 ReLU
  out[(size_t)node * 64 + lane] = (u32)f2bf(r0) | ((u32)f2bf(r1) << 16);
}

// 64 channels: 1 wave/node, 1 ch per lane; no ReLU; output dtype per flags[0]
__global__ __launch_bounds__(256) void agg_64(const u16* __restrict__ H,
                                              const int* __restrict__ rp,
                                              const int* __restrict__ cs,
                                              const float* __restrict__ dinv,
                                              const void* __restrict__ biasv,
                                              const int* __restrict__ flags,
                                              void* __restrict__ outv, int n) {
  int node = blockIdx.x * 4 + (threadIdx.x >> 6);
  if (node >= n) return;
  int lane = threadIdx.x & 63;
  int s0 = rp[node], s1 = rp[node + 1];
  float a = 0.f;
  for (int base = s0; base < s1; base += 64) {
    int nb = s1 - base; if (nb > 64) nb = 64;
    int src = 0; float dv = 0.f;
    if (lane < nb) { src = cs[base + lane]; dv = dinv[src]; }
    int j = 0;
    for (; j + 4 <= nb; j += 4) {
      int s_0 = __shfl(src, j), s_1 = __shfl(src, j + 1);
      int s_2 = __shfl(src, j + 2), s_3 = __shfl(src, j + 3);
      float w_0 = __shfl(dv, j), w_1 = __shfl(dv, j + 1);
      float w_2 = __shfl(dv, j + 2), w_3 = __shfl(dv, j + 3);
      float f0 = bf2f(H[(size_t)s_0 * 64 + lane]);
      float f1 = bf2f(H[(size_t)s_1 * 64 + lane]);
      float f2 = bf2f(H[(size_t)s_2 * 64 + lane]);
      float f3 = bf2f(H[(size_t)s_3 * 64 + lane]);
      a += w_0 * f0; a += w_1 * f1; a += w_2 * f2; a += w_3 * f3;
    }
    for (; j < nb; j++) {
      int sj = __shfl(src, j);
      float wj = __shfl(dv, j);
      a += wj * bf2f(H[(size_t)sj * 64 + lane]);
    }
  }
  float ds = dinv[node];
  float fs = bf2f(H[(size_t)node * 64 + lane]);
  float bz = flags[0] ? ((const float*)biasv)[lane] : bf2f(((const u16*)biasv)[lane]);
  float r = ds * (a + ds * fs) + bz;
  if (flags[0]) ((float*)outv)[(size_t)node * 64 + lane] = r;
  else          ((u16*)outv)[(size_t)node * 64 + lane] = f2bf(r);
}

// ---------------- launch ----------------

extern "C" void kernel_launch(void* const* d_in, const int* in_sizes, int n_in,
                              void* d_out, int out_size, void* d_ws, size_t ws_size,
                              hipStream_t stream) {
  const void* x  = d_in[0];
  const int*  ei = (const int*)d_in[1];
  const void* W1 = d_in[2];
  const void* b1 = d_in[3];
  const void* W2 = d_in[4];
  const void* b2 = d_in[5];
  const int N = in_sizes[0] / 128;
  const int E = in_sizes[1] / 2;

  auto al = [](size_t v) { return (v + 15) & ~(size_t)15; };
  char* ws = (char*)d_ws;
  size_t o = 0;
  int*   flags = (int*)(ws + o); o += 256;
  int*   deg  = (int*)(ws + o);   o += al((size_t)N * 4);        // reused as cnt for fill
  int*   rp   = (int*)(ws + o);   o += al((size_t)(N + 1) * 4);
  float* dinv = (float*)(ws + o); o += al((size_t)N * 4);
  int*   csr  = (int*)(ws + o);   o += al((size_t)E * 4);
  u16*   h    = (u16*)(ws + o);   o += al((size_t)N * 128 * 2);  // layer1 pre-agg; reused as h2
  u16*   h1   = (u16*)(ws + o);   o += al((size_t)N * 128 * 2);  // layer1 post-agg (ReLU)
  int*   bsum = (int*)(ws + o);   o += 4096;
  u16*   h2   = h;  // gemm2 reads h1, writes here; h dead by then

  const int gE = (E + 255) / 256;
  const int gN = (N + 255) / 256;
  const int nb = (N + 1023) / 1024;

  probe_dtypes<<<1, 64, 0, stream>>>((const u16*)x, (const u32*)ei, flags);
  hipMemsetAsync(deg, 0, (size_t)N * 4, stream);
  count_deg<<<gE, 256, 0, stream>>>(ei, flags, deg, E);
  compute_dinv<<<gN, 256, 0, stream>>>(deg, dinv, N);
  scan_block<<<nb, 1024, 0, stream>>>(deg, rp, bsum, N);
  scan_tops<<<1, 64, 0, stream>>>(bsum, nb);
  scan_add<<<gN, 256, 0, stream>>>(rp, bsum, N);
  hipMemsetAsync(deg, 0, (size_t)N * 4, stream);  // now the fill counters
  fill_csr_part<<<8 * 160, 256, 0, stream>>>(ei, flags, rp, deg, csr, E, N);

  // gemm1: X = harness input (dtype per probe). gemm2: X = internal bf16 h1 (ALWAYS bf16).
  gemm_x_w<128, true><<<(N + 63) / 64, 256, 0, stream>>>(x, W1, flags, h, N);
  agg_128<<<(N + 3) / 4, 256, 0, stream>>>((const u32*)h, rp, csr, dinv, b1, flags, (u32*)h1, N);
  gemm_x_w<64, false><<<(N + 63) / 64, 256, 0, stream>>>(h1, W2, flags, h2, N);
  agg_64<<<(N + 3) / 4, 256, 0, stream>>>(h2, rp, csr, dinv, b2, flags, d_out, N);
}

// Round 5
// 612.413 us; speedup vs baseline: 1.3175x; 1.1226x over previous
//
#include <hip/hip_runtime.h>

typedef unsigned int u32;
typedef unsigned short u16;
typedef __bf16 bf16x8 __attribute__((ext_vector_type(8)));
typedef float floatx4 __attribute__((ext_vector_type(4)));
typedef u32 u32x2 __attribute__((ext_vector_type(2)));
typedef float floatx2 __attribute__((ext_vector_type(2)));

__device__ __forceinline__ u16 f2bf(float f) {
  u32 u = __float_as_uint(f);
  u += 0x7fffu + ((u >> 16) & 1u);
  return (u16)(u >> 16);
}
__device__ __forceinline__ float bf2f(u16 h) { return __uint_as_float(((u32)h) << 16); }
__device__ __forceinline__ float bflo(u32 v) { return __uint_as_float(v << 16); }
__device__ __forceinline__ float bfhi(u32 v) { return __uint_as_float(v & 0xffff0000u); }

// ---------------- runtime dtype probe ----------------
// flags[0] = 1 if x/W/b are fp32 (else bf16);  flags[1] = 1 if edge_index is int64 (else int32)
__global__ void probe_dtypes(const u16* __restrict__ xs, const u32* __restrict__ eis,
                             int* __restrict__ flags) {
  int lane = threadIdx.x;  // 64 threads
  int big = 0;
  for (int i = lane; i < 4096; i += 64) {
    u32 e = (xs[i] >> 7) & 0xffu;
    big += (e >= 0xC0u) ? 1 : 0;            // |v| >= 2^65: impossible for N(0,1) bf16
  }
  int odd = 0;
  for (int i = lane; i < 256; i += 64)
    odd += (eis[2 * i + 1] != 0u) ? 1 : 0;  // int64 hi-words of values < 2^31 are all 0
#pragma unroll
  for (int off = 32; off; off >>= 1) {
    big += __shfl_down(big, off);
    odd += __shfl_down(odd, off);
  }
  if (lane == 0 && blockIdx.x == 0) {
    flags[0] = (big > 16) ? 1 : 0;
    flags[1] = (odd == 0) ? 1 : 0;
  }
}

// ---------------- CSR construction ----------------

// Fused: compact edge_index (possibly int64) to int32 src/dst arrays + in-degree count.
__global__ void compact_count(const int* __restrict__ ei, const int* __restrict__ flags,
                              int* __restrict__ src32, int* __restrict__ dst32,
                              int* __restrict__ deg, int e) {
  int i = blockIdx.x * 256 + threadIdx.x;
  if (i < e) {
    int s, d;
    if (flags[1]) { s = ei[2 * i]; d = ei[2 * (e + i)]; }
    else          { s = ei[i];     d = ei[e + i]; }
    src32[i] = s; dst32[i] = d;
    atomicAdd(&deg[d], 1);
  }
}

__global__ void compute_dinv(const int* __restrict__ deg, float* __restrict__ dinv, int n) {
  int i = blockIdx.x * 256 + threadIdx.x;
  if (i < n) dinv[i] = rsqrtf((float)(deg[i] + 1));  // +1 self-loop, always > 0
}

__global__ __launch_bounds__(1024) void scan_block(const int* __restrict__ deg,
                                                   int* __restrict__ rp,
                                                   int* __restrict__ bsum, int n) {
  __shared__ int sm[1024];
  int gid = blockIdx.x * 1024 + threadIdx.x;
  int x = (gid < n) ? deg[gid] : 0;
  sm[threadIdx.x] = x;
  __syncthreads();
  for (int off = 1; off < 1024; off <<= 1) {
    int t = (threadIdx.x >= off) ? sm[threadIdx.x - off] : 0;
    __syncthreads();
    sm[threadIdx.x] += t;
    __syncthreads();
  }
  if (gid < n) rp[gid + 1] = sm[threadIdx.x];  // inclusive within block
  if (threadIdx.x == 1023) bsum[blockIdx.x] = sm[1023];
}

__global__ void scan_tops(int* __restrict__ bsum, int nb) {
  if (blockIdx.x == 0 && threadIdx.x == 0) {
    int run = 0;
    for (int b = 0; b < nb; b++) { int t = bsum[b]; bsum[b] = run; run += t; }
  }
}

__global__ void scan_add(int* __restrict__ rp, const int* __restrict__ bsum, int n) {
  int i = blockIdx.x * 256 + threadIdx.x;
  if (i == 0) rp[0] = 0;
  if (i < n) rp[i + 1] += bsum[i >> 10];
}

// Partitioned fill over compact int32 arrays: blocks with (blockIdx&7)==p only write csr
// slots for dst in slice p -> slice writes stay in ONE XCD's L2 -> full-line writebacks
// (fixed the 197 MB WRITE_SIZE in round 3). Heuristic affects speed only.
__global__ __launch_bounds__(256) void fill_csr_part(const int* __restrict__ src32,
                                                     const int* __restrict__ dst32,
                                                     const int* __restrict__ rp,
                                                     int* __restrict__ cnt,
                                                     int* __restrict__ csr, int e, int n) {
  const int part = blockIdx.x & 7;
  const int bid = blockIdx.x >> 3;
  const int nblk = gridDim.x >> 3;
  const int slice = (n + 7) >> 3;
  const int lo = part * slice;
  const int hi = (lo + slice < n) ? lo + slice : n;
  for (int i = bid * 256 + threadIdx.x; i < e; i += nblk * 256) {
    int d = dst32[i];
    if (d >= lo && d < hi) {
      int s = src32[i];
      int pos = rp[d] + atomicAdd(&cnt[d], 1);
      csr[pos] = s;
    }
  }
}

// ---------------- bf16 MFMA GEMM: Y[nrows,128] @ W[128,OUT] ----------------
// A-frag: A[m=lane&15][k=(lane>>4)*8+j]; B-frag: B[k=(lane>>4)*8+j][n=lane&15]
// C/D: col=lane&15, row=(lane>>4)*4+reg  (m89/m91-verified mapping)
// XPROBED: X is a harness input, dtype per flags[0]. Otherwise X is internal bf16 ALWAYS.

template <int OUT, bool XPROBED>
__global__ __launch_bounds__(256) void gemm_x_w(const void* __restrict__ Xv,
                                                const void* __restrict__ Wv,
                                                const int* __restrict__ flags,
                                                u16* __restrict__ Y, int nrows) {
  constexpr int K = 128;
  constexpr int NT = OUT / 16;
  constexpr int LDW = K + 8;
  __shared__ u16 Wt[OUT * LDW];
  const int wf32 = flags[0];
  const int xf32 = XPROBED ? wf32 : 0;
  int tid = threadIdx.x;
  if (wf32) {
    const float* Wf = (const float*)Wv;
    for (int idx = tid; idx < K * OUT; idx += 256) {
      int k = idx / OUT, n = idx % OUT;
      Wt[n * LDW + k] = f2bf(Wf[idx]);
    }
  } else {
    const u16* Wu = (const u16*)Wv;
    for (int idx = tid; idx < K * OUT; idx += 256) {
      int k = idx / OUT, n = idx % OUT;
      Wt[n * LDW + k] = Wu[idx];
    }
  }
  __syncthreads();
  int lane = tid & 63, wave = tid >> 6;
  int quad = lane >> 4, low = lane & 15;
  int mBase = blockIdx.x * 64 + wave * 16;
  int m = mBase + low;
  int ml = (m < nrows) ? m : (nrows - 1);  // clamp: rows independent, stores guarded
  floatx4 acc[NT];
#pragma unroll
  for (int i = 0; i < NT; i++) acc[i] = (floatx4)0.0f;
#pragma unroll
  for (int kb = 0; kb < 4; kb++) {
    int k0 = kb * 32 + quad * 8;
    bf16x8 a;
    if (xf32) {
      const float* Xf = (const float*)Xv;
      floatx4 p0 = *(const floatx4*)(Xf + (size_t)ml * K + k0);
      floatx4 p1 = *(const floatx4*)(Xf + (size_t)ml * K + k0 + 4);
      union { bf16x8 v; u16 s[8]; } au;
#pragma unroll
      for (int j = 0; j < 4; j++) { au.s[j] = f2bf(p0[j]); au.s[4 + j] = f2bf(p1[j]); }
      a = au.v;
    } else {
      a = *(const bf16x8*)((const u16*)Xv + (size_t)ml * K + k0);
    }
#pragma unroll
    for (int nt = 0; nt < NT; nt++) {
      bf16x8 b = *(const bf16x8*)(&Wt[(nt * 16 + low) * LDW + k0]);
      acc[nt] = __builtin_amdgcn_mfma_f32_16x16x32_bf16(a, b, acc[nt], 0, 0, 0);
    }
  }
#pragma unroll
  for (int nt = 0; nt < NT; nt++) {
    int col = nt * 16 + low;
#pragma unroll
    for (int r = 0; r < 4; r++) {
      int row = mBase + quad * 4 + r;
      if (row < nrows) Y[(size_t)row * OUT + col] = f2bf(acc[nt][r]);
    }
  }
}

// ---------------- aggregation: out[d] = act( dinv[d]*(sum_e dinv[s]*h[s] + dinv[d]*h[d]) + b ) ----
// Pair-packed gathers: lane = 32*eh + c. eh in {0,1} selects edge of a pair, c selects the
// channel group. One 64-lane load = 2 edges. Lanes >= nb hold dv=0 -> pad slots contribute 0
// (their gathers hit row 0, one L1 line). Cross-half combine via shfl_xor(32) at the end.

// 128 channels: lane c handles ch 4c..4c+3 (u32x2 = dwordx2 per edge-half)
__global__ __launch_bounds__(256) void agg_128(const u32* __restrict__ H,
                                               const int* __restrict__ rp,
                                               const int* __restrict__ cs,
                                               const float* __restrict__ dinv,
                                               const void* __restrict__ biasv,
                                               const int* __restrict__ flags,
                                               u32* __restrict__ out, int n) {
  int node = blockIdx.x * 4 + (threadIdx.x >> 6);
  if (node >= n) return;
  int lane = threadIdx.x & 63;
  int eh = lane >> 5, c = lane & 31;
  int s0 = rp[node], s1 = rp[node + 1];
  float a0 = 0.f, a1 = 0.f, a2 = 0.f, a3 = 0.f;
  for (int base = s0; base < s1; base += 64) {
    int nb = s1 - base; if (nb > 64) nb = 64;
    int src = 0; float dv = 0.f;
    if (lane < nb) { src = cs[base + lane]; dv = dinv[src]; }
    for (int j = 0; j < nb; j += 8) {   // 8 edges/iter, 4 dwordx2 loads in flight
#pragma unroll
      for (int p = 0; p < 4; p++) {
        int idx = j + 2 * p + eh;       // <= 63 always (j<=56)
        int sj = __shfl(src, idx);
        float wj = __shfl(dv, idx);
        u32x2 v = *(const u32x2*)(H + (size_t)sj * 64 + 2 * c);
        a0 += wj * bflo(v.x); a1 += wj * bfhi(v.x);
        a2 += wj * bflo(v.y); a3 += wj * bfhi(v.y);
      }
    }
  }
  a0 += __shfl_xor(a0, 32); a1 += __shfl_xor(a1, 32);
  a2 += __shfl_xor(a2, 32); a3 += __shfl_xor(a3, 32);
  float ds = dinv[node];
  u32x2 vs = *(const u32x2*)(H + (size_t)node * 64 + 2 * c);
  float r0 = ds * (a0 + ds * bflo(vs.x));
  float r1 = ds * (a1 + ds * bfhi(vs.x));
  float r2 = ds * (a2 + ds * bflo(vs.y));
  float r3 = ds * (a3 + ds * bfhi(vs.y));
  float b0, b1, b2, b3;
  if (flags[0]) {
    floatx4 bf = *(const floatx4*)((const float*)biasv + 4 * c);
    b0 = bf[0]; b1 = bf[1]; b2 = bf[2]; b3 = bf[3];
  } else {
    u32x2 bb = *(const u32x2*)((const u32*)biasv + 2 * c);
    b0 = bflo(bb.x); b1 = bfhi(bb.x); b2 = bflo(bb.y); b3 = bfhi(bb.y);
  }
  r0 = fmaxf(r0 + b0, 0.f); r1 = fmaxf(r1 + b1, 0.f);   // layer-1 ReLU
  r2 = fmaxf(r2 + b2, 0.f); r3 = fmaxf(r3 + b3, 0.f);
  if (eh == 0) {
    u32x2 o;
    o.x = (u32)f2bf(r0) | ((u32)f2bf(r1) << 16);
    o.y = (u32)f2bf(r2) | ((u32)f2bf(r3) << 16);
    *(u32x2*)(out + (size_t)node * 64 + 2 * c) = o;
  }
}

// 64 channels: lane c handles ch 2c,2c+1 (u32 per edge-half); no ReLU; out dtype per flags[0]
__global__ __launch_bounds__(256) void agg_64(const u16* __restrict__ Hu,
                                              const int* __restrict__ rp,
                                              const int* __restrict__ cs,
                                              const float* __restrict__ dinv,
                                              const void* __restrict__ biasv,
                                              const int* __restrict__ flags,
                                              void* __restrict__ outv, int n) {
  const u32* H = (const u32*)Hu;  // 32 u32 per row
  int node = blockIdx.x * 4 + (threadIdx.x >> 6);
  if (node >= n) return;
  int lane = threadIdx.x & 63;
  int eh = lane >> 5, c = lane & 31;
  int s0 = rp[node], s1 = rp[node + 1];
  float a0 = 0.f, a1 = 0.f;
  for (int base = s0; base < s1; base += 64) {
    int nb = s1 - base; if (nb > 64) nb = 64;
    int src = 0; float dv = 0.f;
    if (lane < nb) { src = cs[base + lane]; dv = dinv[src]; }
    for (int j = 0; j < nb; j += 8) {
#pragma unroll
      for (int p = 0; p < 4; p++) {
        int idx = j + 2 * p + eh;
        int sj = __shfl(src, idx);
        float wj = __shfl(dv, idx);
        u32 v = H[(size_t)sj * 32 + c];
        a0 += wj * bflo(v); a1 += wj * bfhi(v);
      }
    }
  }
  a0 += __shfl_xor(a0, 32); a1 += __shfl_xor(a1, 32);
  float ds = dinv[node];
  u32 vs = H[(size_t)node * 32 + c];
  float r0 = ds * (a0 + ds * bflo(vs));
  float r1 = ds * (a1 + ds * bfhi(vs));
  if (flags[0]) {
    floatx2 bf = *(const floatx2*)((const float*)biasv + 2 * c);
    r0 += bf[0]; r1 += bf[1];
    if (eh == 0) {
      floatx2 o; o[0] = r0; o[1] = r1;
      *(floatx2*)((float*)outv + (size_t)node * 64 + 2 * c) = o;
    }
  } else {
    u32 bb = ((const u32*)biasv)[c];
    r0 += bflo(bb); r1 += bfhi(bb);
    if (eh == 0)
      ((u32*)outv)[(size_t)node * 32 + c] = (u32)f2bf(r0) | ((u32)f2bf(r1) << 16);
  }
}

// ---------------- launch ----------------

extern "C" void kernel_launch(void* const* d_in, const int* in_sizes, int n_in,
                              void* d_out, int out_size, void* d_ws, size_t ws_size,
                              hipStream_t stream) {
  const void* x  = d_in[0];
  const int*  ei = (const int*)d_in[1];
  const void* W1 = d_in[2];
  const void* b1 = d_in[3];
  const void* W2 = d_in[4];
  const void* b2 = d_in[5];
  const int N = in_sizes[0] / 128;
  const int E = in_sizes[1] / 2;

  auto al = [](size_t v) { return (v + 255) & ~(size_t)255; };
  char* ws = (char*)d_ws;
  size_t o = 0;
  int*   flags = (int*)(ws + o);  o += 256;
  int*   deg  = (int*)(ws + o);   o += al((size_t)N * 4);        // reused as cnt for fill
  int*   rp   = (int*)(ws + o);   o += al((size_t)(N + 1) * 4);
  float* dinv = (float*)(ws + o); o += al((size_t)N * 4);
  int*   csr  = (int*)(ws + o);   o += al((size_t)E * 4);
  u16*   h    = (u16*)(ws + o);   o += al((size_t)N * 128 * 2);  // layer1 pre-agg; reused as h2
  u16*   h1   = (u16*)(ws + o);   o += al((size_t)N * 128 * 2);  // layer1 post-agg (ReLU)
  int*   bsum = (int*)(ws + o);   o += 4096;
  u16*   h2   = h;  // gemm2 reads h1, writes here; h dead by then
  // src32/dst32 alias h1: only live until fill_csr_part; h1 first written by agg_128 (later).
  int*   src32 = (int*)h1;
  int*   dst32 = src32 + E;

  const int gE = (E + 255) / 256;
  const int gN = (N + 255) / 256;
  const int nb = (N + 1023) / 1024;

  probe_dtypes<<<1, 64, 0, stream>>>((const u16*)x, (const u32*)ei, flags);
  hipMemsetAsync(deg, 0, (size_t)N * 4, stream);
  compact_count<<<gE, 256, 0, stream>>>(ei, flags, src32, dst32, deg, E);
  compute_dinv<<<gN, 256, 0, stream>>>(deg, dinv, N);
  scan_block<<<nb, 1024, 0, stream>>>(deg, rp, bsum, N);
  scan_tops<<<1, 64, 0, stream>>>(bsum, nb);
  scan_add<<<gN, 256, 0, stream>>>(rp, bsum, N);
  hipMemsetAsync(deg, 0, (size_t)N * 4, stream);  // now the fill counters
  fill_csr_part<<<8 * 160, 256, 0, stream>>>(src32, dst32, rp, deg, csr, E, N);

  // gemm1: X = harness input (dtype per probe). gemm2: X = internal bf16 h1 (ALWAYS bf16).
  gemm_x_w<128, true><<<(N + 63) / 64, 256, 0, stream>>>(x, W1, flags, h, N);
  agg_128<<<(N + 3) / 4, 256, 0, stream>>>((const u32*)h, rp, csr, dinv, b1, flags, (u32*)h1, N);
  gemm_x_w<64, false><<<(N + 63) / 64, 256, 0, stream>>>(h1, W2, flags, h2, N);
  agg_64<<<(N + 3) / 4, 256, 0, stream>>>(h2, rp, csr, dinv, b2, flags, d_out, N);
}